// Round 17
// baseline (122.949 us; speedup 1.0000x reference)
//
#include <hip/hip_runtime.h>
#include <stdint.h>

#define Bdim 512
#define Tdim 2000
#define Ddim 20
#define Hdim 128
#define Cdim 10
#define TT   64
#define NCH  32              // 31 full chunks + 16-step tail
#define BETA 0.95f
#define THR  0.8f

typedef float f32x2 __attribute__((ext_vector_type(2)));
typedef float f32x4 __attribute__((ext_vector_type(4)));
typedef int   i32x4 __attribute__((ext_vector_type(4)));

// f32 pair -> packed bf16 hi + packed bf16 lo (RNE)
#define CVT_HILO(HI, LO, F0, F1) {                                                     \
    asm volatile("v_cvt_pk_bf16_f32 %0, %1, %2" : "=v"(HI) : "v"(F0), "v"(F1));        \
    const float h0f_ = __uint_as_float((HI) << 16);                                    \
    const float h1f_ = __uint_as_float((HI) & 0xFFFF0000u);                            \
    const float l0_ = (F0) - h0f_;  const float l1_ = (F1) - h1f_;                     \
    asm volatile("v_cvt_pk_bf16_f32 %0, %1, %2" : "=v"(LO) : "v"(l0_), "v"(l1_)); }

#define MFMA0(ACC, A8, B8) \
  asm volatile("v_mfma_f32_16x16x32_bf16 %0, %1, %2, 0"  : "=v"(ACC) : "v"(A8), "v"(B8));
#define MFMA(ACC, A8, B8)  \
  asm volatile("v_mfma_f32_16x16x32_bf16 %0, %1, %2, %0" : "+v"(ACC) : "v"(A8), "v"(B8));

__global__ __launch_bounds__(256, 1) void snn_spec6_kernel(
    const float* __restrict__ x,   // [B,T,D]
    const float* __restrict__ W1,  // [H,D]
    const float* __restrict__ b1,  // [H]
    const float* __restrict__ W2,  // [C,H]
    const float* __restrict__ b2,  // [C]
    float* __restrict__ out)       // [B,C]
{
  const int b   = blockIdx.x;
  const int tid = threadIdx.x;    // 0..255
  const int wid = tid >> 6;
  const int l   = tid & 63;
  const int r   = l & 15;
  const int g   = l >> 4;

  // Role flip by block parity (r15-proven): co-resident blocks mix P/S per SIMD.
  const bool flip = ((b >> 8) & 1) != 0;
  const bool isP  = flip ? (wid >= 2) : (wid < 2);
  const int  pwid = wid & 1;      // producer index 0/1 (owns t-tiles 2p, 2p+1)
  const int  swid = wid & 1;      // scanner index 0/1 (owns h 64s..64s+63)

  __shared__ __align__(16) float xraw[2][TT * Ddim];    // 10240 B
  __shared__ __align__(16) float cur[2][Hdim * 66];     // 67584 B, h-major, stride 66 dw
  __shared__ float cnt_s[Hdim];

  const float* xb = x + (size_t)b * (Tdim * Ddim);
  const float* const clampMax = x + (size_t)Bdim * Tdim * Ddim - 4;

  const uint32_t xrawB = (uint32_t)(uintptr_t)&xraw[0][0];
  const uint32_t curB  = (uint32_t)(uintptr_t)&cur[0][0];

  // ---------------- producer-only setup ----------------
  i32x4 bhi[8], blo[8];
  f32x4 zero4, ovr;
  bool  sel23 = false, g3f = false;
  if (isP) {
    const bool g2 = (g == 2);
    g3f   = (g == 3);
    sel23 = g2 | g3f;
    zero4[0]=0.f; zero4[1]=0.f; zero4[2]=0.f; zero4[3]=0.f;
    ovr = zero4; if (g2) ovr[0] = 1.0f;    // bias rider at k=20
#pragma unroll
    for (int ni = 0; ni < 8; ++ni) {
      const int hh = ni * 16 + r;
      float wv[8];
#pragma unroll
      for (int j = 0; j < 8; ++j) {
        const int k = 8 * g + j;
        wv[j] = (k < Ddim) ? W1[hh * Ddim + k] : ((k == Ddim) ? b1[hh] : 0.0f);
      }
#pragma unroll
      for (int d = 0; d < 4; ++d) {
        const uint32_t u0 = __float_as_uint(wv[2*d]), u1 = __float_as_uint(wv[2*d+1]);
        const uint32_t h0 = (u0 + 0x8000u) & 0xFFFF0000u;
        const uint32_t h1 = (u1 + 0x8000u) & 0xFFFF0000u;
        bhi[ni][d] = (int)(h1 | (h0 >> 16));
        const float l0 = wv[2*d]   - __uint_as_float(h0);
        const float l1 = wv[2*d+1] - __uint_as_float(h1);
        const uint32_t e0 = (__float_as_uint(l0) + 0x8000u) & 0xFFFF0000u;
        const uint32_t e1 = (__float_as_uint(l1) + 0x8000u) & 0xFFFF0000u;
        blo[ni][d] = (int)(e1 | (e0 >> 16));
      }
    }
  }

  // ---------------- scanner-only state ----------------
  float    mem = 0.0f;
  bool     sp  = false;
  uint32_t cnt = 0u;
  f32x2    negT2; negT2[0] = -THR; negT2[1] = -THR;

#define STAGE(CH, BUF) do {                                                            \
    const float* g0_ = xb + (CH) * 1280 + pwid * 640 + l * 4;                          \
    char* lb_ = (char*)&xraw[0][0] + (BUF) * 5120 + pwid * 2560 + l * 16;              \
    const float* p0_ = g0_;        if (p0_ > clampMax) p0_ = clampMax;                 \
    const float* p1_ = g0_ + 256;  if (p1_ > clampMax) p1_ = clampMax;                 \
    __builtin_amdgcn_global_load_lds(                                                  \
      (const __attribute__((address_space(1))) unsigned int*)p0_,                      \
      (__attribute__((address_space(3))) unsigned int*)lb_, 16, 0, 0);                 \
    __builtin_amdgcn_global_load_lds(                                                  \
      (const __attribute__((address_space(1))) unsigned int*)p1_,                      \
      (__attribute__((address_space(3))) unsigned int*)(lb_ + 1024), 16, 0, 0);        \
    if (l < 32) {                                                                      \
      const float* p2_ = g0_ + 512;  if (p2_ > clampMax) p2_ = clampMax;               \
      __builtin_amdgcn_global_load_lds(                                                \
        (const __attribute__((address_space(1))) unsigned int*)p2_,                    \
        (__attribute__((address_space(3))) unsigned int*)(lb_ + 2048), 16, 0, 0);      \
    } } while (0)

#define VM0()  asm volatile("s_waitcnt vmcnt(0)" ::: "memory");
#define LGW(N) asm volatile("s_waitcnt lgkmcnt(" #N ")" ::: "memory"); __builtin_amdgcn_sched_barrier(0);
#define BAR()  __builtin_amdgcn_sched_barrier(0); __builtin_amdgcn_s_barrier(); __builtin_amdgcn_sched_barrier(0);

#define SELA(A0, A1) { A0 = g3f ? zero4 : A0;  A1 = sel23 ? ovr : A1; }

#define CVT8(AHI, ALO, A0, A1) {                                                       \
    uint32_t h_, lo_;                                                                  \
    CVT_HILO(h_, lo_, A0[0], A0[1]) AHI[0]=(int)h_; ALO[0]=(int)lo_;                   \
    CVT_HILO(h_, lo_, A0[2], A0[3]) AHI[1]=(int)h_; ALO[1]=(int)lo_;                   \
    CVT_HILO(h_, lo_, A1[0], A1[1]) AHI[2]=(int)h_; ALO[2]=(int)lo_;                   \
    CVT_HILO(h_, lo_, A1[2], A1[3]) AHI[3]=(int)h_; ALO[3]=(int)lo_; }

#define MM24(AHI, ALO, C0,C1,C2,C3,C4,C5,C6,C7)                                        \
    MFMA0(C0, ALO, bhi[0]) MFMA0(C1, ALO, bhi[1]) MFMA0(C2, ALO, bhi[2])               \
    MFMA0(C3, ALO, bhi[3]) MFMA0(C4, ALO, bhi[4]) MFMA0(C5, ALO, bhi[5])               \
    MFMA0(C6, ALO, bhi[6]) MFMA0(C7, ALO, bhi[7])                                      \
    MFMA (C0, AHI, blo[0]) MFMA (C1, AHI, blo[1]) MFMA (C2, AHI, blo[2])               \
    MFMA (C3, AHI, blo[3]) MFMA (C4, AHI, blo[4]) MFMA (C5, AHI, blo[5])               \
    MFMA (C6, AHI, blo[6]) MFMA (C7, AHI, blo[7])                                      \
    MFMA (C0, AHI, bhi[0]) MFMA (C1, AHI, bhi[1]) MFMA (C2, AHI, bhi[2])               \
    MFMA (C3, AHI, bhi[3]) MFMA (C4, AHI, bhi[4]) MFMA (C5, AHI, bhi[5])               \
    MFMA (C6, AHI, bhi[6]) MFMA (C7, AHI, bhi[7])

  // h-major C-write (r14-verified mapping): h = 16*NI + r, t = tilebase + 4g + reg.
  // One b128 per NI: addr = curB + pbuf*33792 + 4224*NI + 264*r + tilebase*4 + 16*g
#define WQ(CWB, AC, NI) \
    asm volatile("ds_write_b128 %0, %1 offset:%c2" :: "v"(CWB), "v"(AC), "n"(4224*(NI)));
#define WTILE8(CWB, P0,P1,P2,P3,P4,P5,P6,P7)                                           \
    WQ(CWB,P0,0) WQ(CWB,P1,1) WQ(CWB,P2,2) WQ(CWB,P3,3)                                \
    WQ(CWB,P4,4) WQ(CWB,P5,5) WQ(CWB,P6,6) WQ(CWB,P7,7)

#define GEMM2() {                                                                      \
    const uint32_t afb_ = xrawB + (uint32_t)(pbuf * 5120 + (2*pwid) * 1280 + 80 * r + 32 * g); \
    f32x4 a00_, a01_, a10_, a11_;                                                      \
    asm volatile("ds_read_b128 %0, %1 offset:0"    : "=v"(a00_) : "v"(afb_));          \
    asm volatile("ds_read_b128 %0, %1 offset:16"   : "=v"(a01_) : "v"(afb_));          \
    asm volatile("ds_read_b128 %0, %1 offset:1280" : "=v"(a10_) : "v"(afb_));          \
    asm volatile("ds_read_b128 %0, %1 offset:1296" : "=v"(a11_) : "v"(afb_));          \
    LGW(2)                                                                             \
    SELA(a00_, a01_)                                                                   \
    i32x4 ahi0_, alo0_;  CVT8(ahi0_, alo0_, a00_, a01_)                                \
    asm volatile("s_nop 2");                                                           \
    f32x4 c00,c01,c02,c03,c04,c05,c06,c07;                                             \
    MM24(ahi0_, alo0_, c00,c01,c02,c03,c04,c05,c06,c07)                                \
    LGW(0)                                                                             \
    SELA(a10_, a11_)                                                                   \
    i32x4 ahi1_, alo1_;  CVT8(ahi1_, alo1_, a10_, a11_)                                \
    asm volatile("s_nop 2");                                                           \
    f32x4 c10,c11,c12,c13,c14,c15,c16,c17;                                             \
    MM24(ahi1_, alo1_, c10,c11,c12,c13,c14,c15,c16,c17)                                \
    asm volatile("s_nop 7"); asm volatile("s_nop 4");                                  \
    const uint32_t cwA_ = curB + (uint32_t)(pbuf * 33792 + 264 * r + 128 * pwid + 16 * g); \
    WTILE8(cwA_,       c00,c01,c02,c03,c04,c05,c06,c07)                                \
    WTILE8(cwA_ + 64u, c10,c11,c12,c13,c14,c15,c16,c17) }

#define GEMM_TAIL() {                                                                  \
    const uint32_t afb_ = xrawB + (uint32_t)(pbuf * 5120 + 80 * r + 32 * g);           \
    f32x4 a00_, a01_;                                                                  \
    asm volatile("ds_read_b128 %0, %1 offset:0"  : "=v"(a00_) : "v"(afb_));            \
    asm volatile("ds_read_b128 %0, %1 offset:16" : "=v"(a01_) : "v"(afb_));            \
    LGW(0)                                                                             \
    SELA(a00_, a01_)                                                                   \
    i32x4 ahi0_, alo0_;  CVT8(ahi0_, alo0_, a00_, a01_)                                \
    asm volatile("s_nop 2");                                                           \
    f32x4 c00,c01,c02,c03,c04,c05,c06,c07;                                             \
    MM24(ahi0_, alo0_, c00,c01,c02,c03,c04,c05,c06,c07)                                \
    asm volatile("s_nop 7"); asm volatile("s_nop 4");                                  \
    const uint32_t cwT_ = curB + (uint32_t)(pbuf * 33792 + 264 * r + 16 * g);          \
    WTILE8(cwT_, c00,c01,c02,c03,c04,c05,c06,c07) }

  // ---- scanner: one b128 = 4 timesteps; r15's CONSUME arithmetic; ring-6 ----
#define RDQ(Q, AD, OFF) \
    asm volatile("ds_read_b128 %0, %1 offset:%c2" : "=v"(Q) : "v"(AD), "n"(OFF));

#define CONSUME2(C0V, C1V) {                                                           \
    float mP_ = fmaf(BETA, mem, C0V);                                                  \
    float mM_ = fmaf(BETA, mem, C0V - THR);                                            \
    mem = sp ? mM_ : mP_;                                                              \
    sp  = mem > THR;                                                                   \
    cnt += sp ? 1u : 0u;                                                               \
    mP_ = fmaf(BETA, mem, C1V);                                                        \
    mM_ = fmaf(BETA, mem, C1V - THR);                                                  \
    mem = sp ? mM_ : mP_;                                                              \
    sp  = mem > THR;                                                                   \
    cnt += sp ? 1u : 0u; }

#define CONSUME4(Q) {                                                                  \
    f32x2 p01_; p01_[0] = Q[0]; p01_[1] = Q[1];                                        \
    f32x2 p23_; p23_[0] = Q[2]; p23_[1] = Q[3];                                        \
    f32x2 cm01_, cm23_;                                                                \
    asm("v_pk_add_f32 %0, %1, %2" : "=v"(cm01_) : "v"(p01_), "v"(negT2));              \
    asm("v_pk_add_f32 %0, %1, %2" : "=v"(cm23_) : "v"(p23_), "v"(negT2));              \
    { float mP_ = fmaf(BETA, mem, Q[0]);                                               \
      float mM_ = fmaf(BETA, mem, cm01_[0]);                                           \
      mem = sp ? mM_ : mP_;  sp = mem > THR;  cnt += sp ? 1u : 0u;                     \
      mP_ = fmaf(BETA, mem, Q[1]);                                                     \
      mM_ = fmaf(BETA, mem, cm01_[1]);                                                 \
      mem = sp ? mM_ : mP_;  sp = mem > THR;  cnt += sp ? 1u : 0u;                     \
      mP_ = fmaf(BETA, mem, Q[2]);                                                     \
      mM_ = fmaf(BETA, mem, cm23_[0]);                                                 \
      mem = sp ? mM_ : mP_;  sp = mem > THR;  cnt += sp ? 1u : 0u;                     \
      mP_ = fmaf(BETA, mem, Q[3]);                                                     \
      mM_ = fmaf(BETA, mem, cm23_[1]);                                                 \
      mem = sp ? mM_ : mP_;  sp = mem > THR;  cnt += sp ? 1u : 0u; } }

  // full chunk: 16 b128 slots (64 t), ring-6, counted lgkm
#define SCAN_FULL(SPB) {                                                               \
    f32x4 q0,q1,q2,q3,q4,q5;                                                           \
    RDQ(q0,SPB,0)  RDQ(q1,SPB,16) RDQ(q2,SPB,32)                                       \
    RDQ(q3,SPB,48) RDQ(q4,SPB,64) RDQ(q5,SPB,80)                                       \
    LGW(5) CONSUME4(q0) RDQ(q0,SPB,96)                                                 \
    LGW(5) CONSUME4(q1) RDQ(q1,SPB,112)                                                \
    LGW(5) CONSUME4(q2) RDQ(q2,SPB,128)                                                \
    LGW(5) CONSUME4(q3) RDQ(q3,SPB,144)                                                \
    LGW(5) CONSUME4(q4) RDQ(q4,SPB,160)                                                \
    LGW(5) CONSUME4(q5) RDQ(q5,SPB,176)                                                \
    LGW(5) CONSUME4(q0) RDQ(q0,SPB,192)                                                \
    LGW(5) CONSUME4(q1) RDQ(q1,SPB,208)                                                \
    LGW(5) CONSUME4(q2) RDQ(q2,SPB,224)                                                \
    LGW(5) CONSUME4(q3) RDQ(q3,SPB,240)                                                \
    LGW(5) CONSUME4(q4)                                                                \
    LGW(4) CONSUME4(q5)                                                                \
    LGW(3) CONSUME4(q0)                                                                \
    LGW(2) CONSUME4(q1)                                                                \
    LGW(1) CONSUME4(q2)                                                                \
    LGW(0) CONSUME4(q3) }

#define SCAN_TAIL(SPB) {                                                               \
    f32x4 q0,q1,q2,q3;                                                                 \
    RDQ(q0,SPB,0) RDQ(q1,SPB,16) RDQ(q2,SPB,32) RDQ(q3,SPB,48)                         \
    LGW(3) CONSUME4(q0)                                                                \
    LGW(2) CONSUME4(q1)                                                                \
    LGW(1) CONSUME4(q2)                                                                \
    LGW(0) CONSUME4(q3) }

  // scanner h-row base: h = swid*64 + l (r14-verified)
  const uint32_t spB0 = curB + (uint32_t)((swid * 64 + l) * 264);

  // ================= main phase loop =================
  if (isP) STAGE(0, 0);

#pragma unroll 1
  for (int ph = 0; ph <= NCH; ++ph) {
    if (isP) {
      if (ph <= NCH - 1) {
        VM0()
        if (ph < NCH - 1) STAGE(ph + 1, (ph + 1) & 1);
        const uint32_t pbuf = (uint32_t)(ph & 1);
        if (ph < NCH - 1) {
          GEMM2()
        } else if (pwid == 0) {
          GEMM_TAIL()
        }
        LGW(0)                                     // cur writes retired
      }
    } else {
      if (ph >= 1) {
        const uint32_t spB = spB0 + (uint32_t)(((ph - 1) & 1) * 33792);
        if (ph - 1 < NCH - 1) { SCAN_FULL(spB) }
        else                  { SCAN_TAIL(spB) }
        if (ph == NCH) cnt_s[swid * 64 + l] = (float)cnt;
      }
    }
    BAR()
  }

  __syncthreads();

  // ---- fused epilogue: logits from spike counts ----
  if (tid < Cdim) {
    float dot = 0.0f;
#pragma unroll
    for (int k = 0; k < Hdim; ++k)
      dot = fmaf(cnt_s[k], W2[tid * Hdim + k], dot);
    const float Tf = (float)Tdim;
    const float scale = 1.0f / Tf + 0.1f / (Tf + 1e-6f);
    out[b * Cdim + tid] = fmaf(dot, scale, 1.1f * b2[tid]);
  }
}

extern "C" void kernel_launch(void* const* d_in, const int* in_sizes, int n_in,
                              void* d_out, int out_size, void* d_ws, size_t ws_size,
                              hipStream_t stream) {
  const float* x  = (const float*)d_in[0];
  const float* W1 = (const float*)d_in[1];
  const float* b1 = (const float*)d_in[2];
  const float* W2 = (const float*)d_in[3];
  const float* b2 = (const float*)d_in[4];
  float* out = (float*)d_out;

  snn_spec6_kernel<<<dim3(Bdim), dim3(256), 0, stream>>>(x, W1, b1, W2, b2, out);
}

// Round 19
// 79.532 us; speedup vs baseline: 1.5459x; 1.5459x over previous
//
#include <hip/hip_runtime.h>
#include <stdint.h>

#define Bdim 512
#define Tdim 2000
#define Ddim 20
#define Hdim 128
#define Cdim 10
#define TT   64
#define NCH  32              // 31 full chunks + 16-step tail
#define BETA 0.95f
#define THR  0.8f

typedef float f32x2 __attribute__((ext_vector_type(2)));
typedef float f32x4 __attribute__((ext_vector_type(4)));
typedef int   i32x4 __attribute__((ext_vector_type(4)));

// f32 pair -> packed bf16 hi + packed bf16 lo (RNE)
#define CVT_HILO(HI, LO, F0, F1) {                                                     \
    asm volatile("v_cvt_pk_bf16_f32 %0, %1, %2" : "=v"(HI) : "v"(F0), "v"(F1));        \
    const float h0f_ = __uint_as_float((HI) << 16);                                    \
    const float h1f_ = __uint_as_float((HI) & 0xFFFF0000u);                            \
    const float l0_ = (F0) - h0f_;  const float l1_ = (F1) - h1f_;                     \
    asm volatile("v_cvt_pk_bf16_f32 %0, %1, %2" : "=v"(LO) : "v"(l0_), "v"(l1_)); }

#define MFMA0(ACC, A8, B8) \
  asm volatile("v_mfma_f32_16x16x32_bf16 %0, %1, %2, 0"  : "=v"(ACC) : "v"(A8), "v"(B8));
#define MFMA(ACC, A8, B8)  \
  asm volatile("v_mfma_f32_16x16x32_bf16 %0, %1, %2, %0" : "+v"(ACC) : "v"(A8), "v"(B8));

__global__ __launch_bounds__(512, 1) void snn_spec8_kernel(
    const float* __restrict__ x,   // [B,T,D]
    const float* __restrict__ W1,  // [H,D]
    const float* __restrict__ b1,  // [H]
    const float* __restrict__ W2,  // [C,H]
    const float* __restrict__ b2,  // [C]
    float* __restrict__ out)       // [B,C]
{
  const int b   = blockIdx.x;
  const int tid = threadIdx.x;    // 0..511
  const int wid = tid >> 6;       // 0..3 producers, 4..7 scanners
  const int l   = tid & 63;
  const int r   = l & 15;
  const int g   = l >> 4;

  // SIMD s hosts wid s (P) and wid s+4 (S) -> automatic 1P+1S per SIMD per block.
  const bool isP  = (wid < 4);
  const int  pwid = wid & 3;      // producer: owns t-tile pwid (16 t)
  const int  swid = wid & 3;      // scanner: owns h in [swid*32, swid*32+32)

  __shared__ __align__(16) float xraw[2][TT * Ddim];    // 10240 B
  __shared__ __align__(16) float cur[2][TT * 132];      // 67584 B, t-major stride 132 dw
  __shared__ float cnt_s[Hdim];

  const float* xb = x + (size_t)b * (Tdim * Ddim);
  const float* const clampMax = x + (size_t)Bdim * Tdim * Ddim - 4;

  const uint32_t xrawB = (uint32_t)(uintptr_t)&xraw[0][0];
  const uint32_t curB  = (uint32_t)(uintptr_t)&cur[0][0];

  // ---------------- producer-only setup (all 128 h) ----------------
  i32x4 bhi[8], blo[8];
  f32x4 zero4, ovr;
  bool  sel23 = false, g3f = false;
  if (isP) {
    const bool g2 = (g == 2);
    g3f   = (g == 3);
    sel23 = g2 | g3f;
    zero4[0]=0.f; zero4[1]=0.f; zero4[2]=0.f; zero4[3]=0.f;
    ovr = zero4; if (g2) ovr[0] = 1.0f;    // bias rider at k=20
#pragma unroll
    for (int ni = 0; ni < 8; ++ni) {
      const int hh = ni * 16 + r;
      float wv[8];
#pragma unroll
      for (int j = 0; j < 8; ++j) {
        const int k = 8 * g + j;
        wv[j] = (k < Ddim) ? W1[hh * Ddim + k] : ((k == Ddim) ? b1[hh] : 0.0f);
      }
#pragma unroll
      for (int d = 0; d < 4; ++d) {
        const uint32_t u0 = __float_as_uint(wv[2*d]), u1 = __float_as_uint(wv[2*d+1]);
        const uint32_t h0 = (u0 + 0x8000u) & 0xFFFF0000u;
        const uint32_t h1 = (u1 + 0x8000u) & 0xFFFF0000u;
        bhi[ni][d] = (int)(h1 | (h0 >> 16));
        const float l0 = wv[2*d]   - __uint_as_float(h0);
        const float l1 = wv[2*d+1] - __uint_as_float(h1);
        const uint32_t e0 = (__float_as_uint(l0) + 0x8000u) & 0xFFFF0000u;
        const uint32_t e1 = (__float_as_uint(l1) + 0x8000u) & 0xFFFF0000u;
        blo[ni][d] = (int)(e1 | (e0 >> 16));
      }
    }
  }

  // ---------------- scanner-only state ----------------
  float    mem = 0.0f;
  bool     sp  = false;
  uint32_t cnt = 0u;
  f32x2    negT2; negT2[0] = -THR; negT2[1] = -THR;

  // WAVE-PRIVATE staging (r18 race fix): each producer stages exactly the
  // 1280-B t-tile it will GEMM (1024-B full-wave DMA + 256-B l<16 DMA), so
  // its own vmcnt(0) covers its entire read set — no cross-wave dependency.
#define STAGE(CH, BUF) do {                                                            \
    const float* g0_ = xb + (CH) * 1280 + pwid * 320 + l * 4;                          \
    char* lb_ = (char*)&xraw[0][0] + (BUF) * 5120 + pwid * 1280 + l * 16;              \
    const float* p0_ = g0_;  if (p0_ > clampMax) p0_ = clampMax;                       \
    __builtin_amdgcn_global_load_lds(                                                  \
      (const __attribute__((address_space(1))) unsigned int*)p0_,                      \
      (__attribute__((address_space(3))) unsigned int*)lb_, 16, 0, 0);                 \
    if (l < 16) {                                                                      \
      const float* p1_ = g0_ + 256;  if (p1_ > clampMax) p1_ = clampMax;               \
      __builtin_amdgcn_global_load_lds(                                                \
        (const __attribute__((address_space(1))) unsigned int*)p1_,                    \
        (__attribute__((address_space(3))) unsigned int*)(lb_ + 1024), 16, 0, 0);      \
    } } while (0)

#define VM0()  asm volatile("s_waitcnt vmcnt(0)" ::: "memory");
#define LGW(N) asm volatile("s_waitcnt lgkmcnt(" #N ")" ::: "memory"); __builtin_amdgcn_sched_barrier(0);
#define BAR()  __builtin_amdgcn_sched_barrier(0); __builtin_amdgcn_s_barrier(); __builtin_amdgcn_sched_barrier(0);

#define CW2(NI, AC)                                                                    \
    asm volatile("ds_write2_b32 %0, %1, %2 offset0:%c3 offset1:%c4"                    \
                 :: "v"(cwb_),  "v"(AC[0]), "v"(AC[1]), "n"(16*(NI)), "n"(16*(NI)+132)); \
    asm volatile("ds_write2_b32 %0, %1, %2 offset0:%c3 offset1:%c4"                    \
                 :: "v"(cwb2_), "v"(AC[2]), "v"(AC[3]), "n"(16*(NI)), "n"(16*(NI)+132));

#define CWRM(MTIDX, P0,P1,P2,P3,P4,P5,P6,P7) {                                         \
    const uint32_t cwb_  = curB + (uint32_t)(pbuf * 33792 + 528 * ((MTIDX) * 16 + 4 * g) + 4 * r); \
    const uint32_t cwb2_ = cwb_ + 1056u;                                               \
    CW2(0,P0) CW2(1,P1) CW2(2,P2) CW2(3,P3) CW2(4,P4) CW2(5,P5) CW2(6,P6) CW2(7,P7) }

#define SELA(A0, A1) { A0 = g3f ? zero4 : A0;  A1 = sel23 ? ovr : A1; }

#define CVT8(AHI, ALO, A0, A1) {                                                       \
    uint32_t h_, lo_;                                                                  \
    CVT_HILO(h_, lo_, A0[0], A0[1]) AHI[0]=(int)h_; ALO[0]=(int)lo_;                   \
    CVT_HILO(h_, lo_, A0[2], A0[3]) AHI[1]=(int)h_; ALO[1]=(int)lo_;                   \
    CVT_HILO(h_, lo_, A1[0], A1[1]) AHI[2]=(int)h_; ALO[2]=(int)lo_;                   \
    CVT_HILO(h_, lo_, A1[2], A1[3]) AHI[3]=(int)h_; ALO[3]=(int)lo_; }

#define MM24(AHI, ALO, C0,C1,C2,C3,C4,C5,C6,C7)                                        \
    MFMA0(C0, ALO, bhi[0]) MFMA0(C1, ALO, bhi[1]) MFMA0(C2, ALO, bhi[2])               \
    MFMA0(C3, ALO, bhi[3]) MFMA0(C4, ALO, bhi[4]) MFMA0(C5, ALO, bhi[5])               \
    MFMA0(C6, ALO, bhi[6]) MFMA0(C7, ALO, bhi[7])                                      \
    MFMA (C0, AHI, blo[0]) MFMA (C1, AHI, blo[1]) MFMA (C2, AHI, blo[2])               \
    MFMA (C3, AHI, blo[3]) MFMA (C4, AHI, blo[4]) MFMA (C5, AHI, blo[5])               \
    MFMA (C6, AHI, blo[6]) MFMA (C7, AHI, blo[7])                                      \
    MFMA (C0, AHI, bhi[0]) MFMA (C1, AHI, bhi[1]) MFMA (C2, AHI, bhi[2])               \
    MFMA (C3, AHI, bhi[3]) MFMA (C4, AHI, bhi[4]) MFMA (C5, AHI, bhi[5])               \
    MFMA (C6, AHI, bhi[6]) MFMA (C7, AHI, bhi[7])

  // one 16-t tile (tile index = pwid): 2 A-reads, 24 MFMA, 16 write2
#define GEMM1() {                                                                      \
    const uint32_t afb_ = xrawB + (uint32_t)(pbuf * 5120 + pwid * 1280 + 80 * r + 32 * g); \
    f32x4 a00_, a01_;                                                                  \
    asm volatile("ds_read_b128 %0, %1 offset:0"  : "=v"(a00_) : "v"(afb_));            \
    asm volatile("ds_read_b128 %0, %1 offset:16" : "=v"(a01_) : "v"(afb_));            \
    LGW(0)                                                                             \
    SELA(a00_, a01_)                                                                   \
    i32x4 ahi0_, alo0_;  CVT8(ahi0_, alo0_, a00_, a01_)                                \
    asm volatile("s_nop 2");                                                           \
    f32x4 c00,c01,c02,c03,c04,c05,c06,c07;                                             \
    MM24(ahi0_, alo0_, c00,c01,c02,c03,c04,c05,c06,c07)                                \
    asm volatile("s_nop 7"); asm volatile("s_nop 4");                                  \
    CWRM(pwid, c00,c01,c02,c03,c04,c05,c06,c07) }

  // ---- scanner (r15-identical): ring-8 read2; one counted wait per 4 t ----
#define RD2A(PR, AD) asm volatile("ds_read2_b32 %0, %1 offset0:0 offset1:132" : "=v"(PR) : "v"(AD));
#define CONSUME(PR) {                                                                  \
    f32x2 cm_; asm("v_pk_add_f32 %0, %1, %2" : "=v"(cm_) : "v"(PR), "v"(negT2));       \
    float mP_ = fmaf(BETA, mem, PR[0]);                                                \
    float mM_ = fmaf(BETA, mem, cm_[0]);                                               \
    mem = sp ? mM_ : mP_;                                                              \
    sp  = mem > THR;                                                                   \
    cnt += sp ? 1u : 0u;                                                               \
    mP_ = fmaf(BETA, mem, PR[1]);                                                      \
    mM_ = fmaf(BETA, mem, cm_[1]);                                                     \
    mem = sp ? mM_ : mP_;                                                              \
    sp  = mem > THR;                                                                   \
    cnt += sp ? 1u : 0u; }

  // slot s covers t = 2s, 2s+1 at byte addr spB + s*1056
#define SFI(RGA, RGB, SA, SB) { LGW(6) CONSUME(pr##RGA) CONSUME(pr##RGB)               \
    { const uint32_t adA_ = spB + (uint32_t)((SA) * 1056); RD2A(pr##RGA, adA_) }       \
    { const uint32_t adB_ = spB + (uint32_t)((SB) * 1056); RD2A(pr##RGB, adB_) } }
#define SFT(RGA, RGB, W) { LGW(W) CONSUME(pr##RGA) CONSUME(pr##RGB) }

#define SCAN_PRE()                                                                     \
    f32x2 pr0, pr1, pr2, pr3, pr4, pr5, pr6, pr7;                                      \
    RD2A(pr0, spB)          RD2A(pr1, spB + 1056u)  RD2A(pr2, spB + 2112u)             \
    RD2A(pr3, spB + 3168u)  RD2A(pr4, spB + 4224u)  RD2A(pr5, spB + 5280u)             \
    RD2A(pr6, spB + 6336u)  RD2A(pr7, spB + 7392u)

#define SCAN_FULL() {                                                                  \
    SCAN_PRE()                                                                         \
    SFI(0,1,  8, 9) SFI(2,3, 10,11) SFI(4,5, 12,13) SFI(6,7, 14,15)                    \
    SFI(0,1, 16,17) SFI(2,3, 18,19) SFI(4,5, 20,21) SFI(6,7, 22,23)                    \
    SFI(0,1, 24,25) SFI(2,3, 26,27) SFI(4,5, 28,29) SFI(6,7, 30,31)                    \
    SFT(0,1,6) SFT(2,3,4) SFT(4,5,2) SFT(6,7,0) }

#define SCAN_TAIL() {                                                                  \
    SCAN_PRE()                                                                         \
    SFT(0,1,6) SFT(2,3,4) SFT(4,5,2) SFT(6,7,0) }

  // scanner h = swid*32 + (l&31); lanes 32-63 duplicate (LDS broadcast, no conflict)
  const uint32_t spB0 = curB + (uint32_t)((swid * 32 + (l & 31)) * 4);

  // ================= main phase loop =================
  if (isP) STAGE(0, 0);

#pragma unroll 1
  for (int ph = 0; ph <= NCH; ++ph) {
    if (isP) {
      if (ph <= NCH - 1) {
        VM0()
        if (ph < NCH - 1) STAGE(ph + 1, (ph + 1) & 1);
        const uint32_t pbuf = (uint32_t)(ph & 1);
        if (ph < NCH - 1) {
          GEMM1()
        } else if (pwid == 0) {        // tail chunk: 16 t = tile 0 only
          GEMM1()
        }
        LGW(0)                         // cur writes retired
      }
    } else {
      if (ph >= 1) {
        const uint32_t spB = spB0 + (uint32_t)(((ph - 1) & 1) * 33792);
        if (ph - 1 < NCH - 1) { SCAN_FULL() }
        else                  { SCAN_TAIL() }
        if (ph == NCH && l < 32) cnt_s[swid * 32 + (l & 31)] = (float)cnt;
      }
    }
    BAR()
  }

  __syncthreads();

  // ---- fused epilogue: logits from spike counts ----
  if (tid < Cdim) {
    float dot = 0.0f;
#pragma unroll
    for (int k = 0; k < Hdim; ++k)
      dot = fmaf(cnt_s[k], W2[tid * Hdim + k], dot);
    const float Tf = (float)Tdim;
    const float scale = 1.0f / Tf + 0.1f / (Tf + 1e-6f);
    out[b * Cdim + tid] = fmaf(dot, scale, 1.1f * b2[tid]);
  }
}

extern "C" void kernel_launch(void* const* d_in, const int* in_sizes, int n_in,
                              void* d_out, int out_size, void* d_ws, size_t ws_size,
                              hipStream_t stream) {
  const float* x  = (const float*)d_in[0];
  const float* W1 = (const float*)d_in[1];
  const float* b1 = (const float*)d_in[2];
  const float* W2 = (const float*)d_in[3];
  const float* b2 = (const float*)d_in[4];
  float* out = (float*)d_out;

  snn_spec8_kernel<<<dim3(Bdim), dim3(512), 0, stream>>>(x, W1, b1, W2, b2, out);
}

// Round 21
// 58.714 us; speedup vs baseline: 2.0940x; 1.3546x over previous
//
#include <hip/hip_runtime.h>
#include <stdint.h>

#define Bdim 512
#define Tdim 2000
#define Ddim 20
#define Hdim 128
#define Cdim 10
#define TT   64
#define NCH  32              // 31 full chunks + 16-step tail
#define BETA 0.95f
#define THR  0.8f

typedef float f32x2 __attribute__((ext_vector_type(2)));
typedef float f32x4 __attribute__((ext_vector_type(4)));
typedef int   i32x4 __attribute__((ext_vector_type(4)));

// f32 pair -> packed bf16 hi + packed bf16 lo (RNE)
#define CVT_HILO(HI, LO, F0, F1) {                                                     \
    asm volatile("v_cvt_pk_bf16_f32 %0, %1, %2" : "=v"(HI) : "v"(F0), "v"(F1));        \
    const float h0f_ = __uint_as_float((HI) << 16);                                    \
    const float h1f_ = __uint_as_float((HI) & 0xFFFF0000u);                            \
    const float l0_ = (F0) - h0f_;  const float l1_ = (F1) - h1f_;                     \
    asm volatile("v_cvt_pk_bf16_f32 %0, %1, %2" : "=v"(LO) : "v"(l0_), "v"(l1_)); }

#define MFMA0(ACC, A8, B8) \
  asm volatile("v_mfma_f32_16x16x32_bf16 %0, %1, %2, 0"  : "=v"(ACC) : "v"(A8), "v"(B8));
#define MFMA(ACC, A8, B8)  \
  asm volatile("v_mfma_f32_16x16x32_bf16 %0, %1, %2, %0" : "+v"(ACC) : "v"(A8), "v"(B8));

__global__ __launch_bounds__(256, 1) void snn_spec4_kernel(
    const float* __restrict__ x,   // [B,T,D]
    const float* __restrict__ W1,  // [H,D]
    const float* __restrict__ b1,  // [H]
    const float* __restrict__ W2,  // [C,H]
    const float* __restrict__ b2,  // [C]
    float* __restrict__ out)       // [B,C]
{
  const int b   = blockIdx.x;
  const int tid = threadIdx.x;    // 0..255
  const int wid = tid >> 6;
  const int l   = tid & 63;
  const int r   = l & 15;
  const int g   = l >> 4;

  // Role flip by block parity: co-resident blocks (b, b+256) then put one
  // producer AND one scanner on every SIMD instead of stacking same roles.
  const bool flip = ((b >> 8) & 1) != 0;
  const bool isP  = flip ? (wid >= 2) : (wid < 2);
  const int  pwid = wid & 1;      // producer index 0/1
  const int  swid = wid & 1;      // scanner index 0/1

  __shared__ __align__(16) float xraw[2][TT * Ddim];    // 10240 B
  __shared__ __align__(16) float cur[2][TT * 132];      // 67584 B, t-major stride 132 dw
  __shared__ float cnt_s[Hdim];

  const float* xb = x + (size_t)b * (Tdim * Ddim);
  const float* const clampMax = x + (size_t)Bdim * Tdim * Ddim - 4;

  const uint32_t xrawB = (uint32_t)(uintptr_t)&xraw[0][0];
  const uint32_t curB  = (uint32_t)(uintptr_t)&cur[0][0];

  // ---------------- producer-only setup ----------------
  i32x4 bhi[8], blo[8];
  f32x4 zero4, ovr;
  bool  sel23 = false, g3f = false;
  if (isP) {
    const bool g2 = (g == 2);
    g3f   = (g == 3);
    sel23 = g2 | g3f;
    zero4[0]=0.f; zero4[1]=0.f; zero4[2]=0.f; zero4[3]=0.f;
    ovr = zero4; if (g2) ovr[0] = 1.0f;    // bias rider at k=20
#pragma unroll
    for (int ni = 0; ni < 8; ++ni) {
      const int hh = ni * 16 + r;
      float wv[8];
#pragma unroll
      for (int j = 0; j < 8; ++j) {
        const int k = 8 * g + j;
        wv[j] = (k < Ddim) ? W1[hh * Ddim + k] : ((k == Ddim) ? b1[hh] : 0.0f);
      }
#pragma unroll
      for (int d = 0; d < 4; ++d) {
        const uint32_t u0 = __float_as_uint(wv[2*d]), u1 = __float_as_uint(wv[2*d+1]);
        const uint32_t h0 = (u0 + 0x8000u) & 0xFFFF0000u;
        const uint32_t h1 = (u1 + 0x8000u) & 0xFFFF0000u;
        bhi[ni][d] = (int)(h1 | (h0 >> 16));
        const float l0 = wv[2*d]   - __uint_as_float(h0);
        const float l1 = wv[2*d+1] - __uint_as_float(h1);
        const uint32_t e0 = (__float_as_uint(l0) + 0x8000u) & 0xFFFF0000u;
        const uint32_t e1 = (__float_as_uint(l1) + 0x8000u) & 0xFFFF0000u;
        blo[ni][d] = (int)(e1 | (e0 >> 16));
      }
    }
  }

  // ---------------- scanner-only state ----------------
  float    mem = 0.0f;
  bool     sp  = false;
  uint32_t cnt = 0u;
  f32x2    negT2; negT2[0] = -THR; negT2[1] = -THR;

#define STAGE(CH, BUF) do {                                                            \
    const float* g0_ = xb + (CH) * 1280 + pwid * 640 + l * 4;                          \
    char* lb_ = (char*)&xraw[0][0] + (BUF) * 5120 + pwid * 2560 + l * 16;              \
    const float* p0_ = g0_;        if (p0_ > clampMax) p0_ = clampMax;                 \
    const float* p1_ = g0_ + 256;  if (p1_ > clampMax) p1_ = clampMax;                 \
    __builtin_amdgcn_global_load_lds(                                                  \
      (const __attribute__((address_space(1))) unsigned int*)p0_,                      \
      (__attribute__((address_space(3))) unsigned int*)lb_, 16, 0, 0);                 \
    __builtin_amdgcn_global_load_lds(                                                  \
      (const __attribute__((address_space(1))) unsigned int*)p1_,                      \
      (__attribute__((address_space(3))) unsigned int*)(lb_ + 1024), 16, 0, 0);        \
    if (l < 32) {                                                                      \
      const float* p2_ = g0_ + 512;  if (p2_ > clampMax) p2_ = clampMax;               \
      __builtin_amdgcn_global_load_lds(                                                \
        (const __attribute__((address_space(1))) unsigned int*)p2_,                    \
        (__attribute__((address_space(3))) unsigned int*)(lb_ + 2048), 16, 0, 0);      \
    } } while (0)

#define VM0()  asm volatile("s_waitcnt vmcnt(0)" ::: "memory");
#define LGW(N) asm volatile("s_waitcnt lgkmcnt(" #N ")" ::: "memory"); __builtin_amdgcn_sched_barrier(0);
#define BAR()  __builtin_amdgcn_sched_barrier(0); __builtin_amdgcn_s_barrier(); __builtin_amdgcn_sched_barrier(0);

#define CW2(NI, AC)                                                                    \
    asm volatile("ds_write2_b32 %0, %1, %2 offset0:%c3 offset1:%c4"                    \
                 :: "v"(cwb_),  "v"(AC[0]), "v"(AC[1]), "n"(16*(NI)), "n"(16*(NI)+132)); \
    asm volatile("ds_write2_b32 %0, %1, %2 offset0:%c3 offset1:%c4"                    \
                 :: "v"(cwb2_), "v"(AC[2]), "v"(AC[3]), "n"(16*(NI)), "n"(16*(NI)+132));

#define CWRM(MTIDX, P0,P1,P2,P3,P4,P5,P6,P7) {                                         \
    const uint32_t cwb_  = curB + (uint32_t)(pbuf * 33792 + 528 * ((MTIDX) * 16 + 4 * g) + 4 * r); \
    const uint32_t cwb2_ = cwb_ + 1056u;                                               \
    CW2(0,P0) CW2(1,P1) CW2(2,P2) CW2(3,P3) CW2(4,P4) CW2(5,P5) CW2(6,P6) CW2(7,P7) }

#define SELA(A0, A1) { A0 = g3f ? zero4 : A0;  A1 = sel23 ? ovr : A1; }

#define CVT8(AHI, ALO, A0, A1) {                                                       \
    uint32_t h_, lo_;                                                                  \
    CVT_HILO(h_, lo_, A0[0], A0[1]) AHI[0]=(int)h_; ALO[0]=(int)lo_;                   \
    CVT_HILO(h_, lo_, A0[2], A0[3]) AHI[1]=(int)h_; ALO[1]=(int)lo_;                   \
    CVT_HILO(h_, lo_, A1[0], A1[1]) AHI[2]=(int)h_; ALO[2]=(int)lo_;                   \
    CVT_HILO(h_, lo_, A1[2], A1[3]) AHI[3]=(int)h_; ALO[3]=(int)lo_; }

#define MM24(AHI, ALO, C0,C1,C2,C3,C4,C5,C6,C7)                                        \
    MFMA0(C0, ALO, bhi[0]) MFMA0(C1, ALO, bhi[1]) MFMA0(C2, ALO, bhi[2])               \
    MFMA0(C3, ALO, bhi[3]) MFMA0(C4, ALO, bhi[4]) MFMA0(C5, ALO, bhi[5])               \
    MFMA0(C6, ALO, bhi[6]) MFMA0(C7, ALO, bhi[7])                                      \
    MFMA (C0, AHI, blo[0]) MFMA (C1, AHI, blo[1]) MFMA (C2, AHI, blo[2])               \
    MFMA (C3, AHI, blo[3]) MFMA (C4, AHI, blo[4]) MFMA (C5, AHI, blo[5])               \
    MFMA (C6, AHI, blo[6]) MFMA (C7, AHI, blo[7])                                      \
    MFMA (C0, AHI, bhi[0]) MFMA (C1, AHI, bhi[1]) MFMA (C2, AHI, bhi[2])               \
    MFMA (C3, AHI, bhi[3]) MFMA (C4, AHI, bhi[4]) MFMA (C5, AHI, bhi[5])               \
    MFMA (C6, AHI, bhi[6]) MFMA (C7, AHI, bhi[7])

  // Both 16-t tiles fused: 4 A-reads upfront, counted waits, all C-writes at end.
#define GEMM2() {                                                                      \
    const uint32_t afb_ = xrawB + (uint32_t)(pbuf * 5120 + (2*pwid) * 1280 + 80 * r + 32 * g); \
    f32x4 a00_, a01_, a10_, a11_;                                                      \
    asm volatile("ds_read_b128 %0, %1 offset:0"    : "=v"(a00_) : "v"(afb_));          \
    asm volatile("ds_read_b128 %0, %1 offset:16"   : "=v"(a01_) : "v"(afb_));          \
    asm volatile("ds_read_b128 %0, %1 offset:1280" : "=v"(a10_) : "v"(afb_));          \
    asm volatile("ds_read_b128 %0, %1 offset:1296" : "=v"(a11_) : "v"(afb_));          \
    LGW(2)                                                                             \
    SELA(a00_, a01_)                                                                   \
    i32x4 ahi0_, alo0_;  CVT8(ahi0_, alo0_, a00_, a01_)                                \
    asm volatile("s_nop 2");                                                           \
    f32x4 c00,c01,c02,c03,c04,c05,c06,c07;                                             \
    MM24(ahi0_, alo0_, c00,c01,c02,c03,c04,c05,c06,c07)                                \
    LGW(0)                                                                             \
    SELA(a10_, a11_)                                                                   \
    i32x4 ahi1_, alo1_;  CVT8(ahi1_, alo1_, a10_, a11_)                                \
    asm volatile("s_nop 2");                                                           \
    f32x4 c10,c11,c12,c13,c14,c15,c16,c17;                                             \
    MM24(ahi1_, alo1_, c10,c11,c12,c13,c14,c15,c16,c17)                                \
    asm volatile("s_nop 7"); asm volatile("s_nop 4");                                  \
    CWRM(2*pwid,     c00,c01,c02,c03,c04,c05,c06,c07)                                  \
    CWRM(2*pwid + 1, c10,c11,c12,c13,c14,c15,c16,c17) }

#define GEMM_TAIL() {                                                                  \
    const uint32_t afb_ = xrawB + (uint32_t)(pbuf * 5120 + 80 * r + 32 * g);           \
    f32x4 a00_, a01_;                                                                  \
    asm volatile("ds_read_b128 %0, %1 offset:0"  : "=v"(a00_) : "v"(afb_));            \
    asm volatile("ds_read_b128 %0, %1 offset:16" : "=v"(a01_) : "v"(afb_));            \
    LGW(0)                                                                             \
    SELA(a00_, a01_)                                                                   \
    i32x4 ahi0_, alo0_;  CVT8(ahi0_, alo0_, a00_, a01_)                                \
    asm volatile("s_nop 2");                                                           \
    f32x4 c00,c01,c02,c03,c04,c05,c06,c07;                                             \
    MM24(ahi0_, alo0_, c00,c01,c02,c03,c04,c05,c06,c07)                                \
    asm volatile("s_nop 7"); asm volatile("s_nop 4");                                  \
    CWRM(0, c00,c01,c02,c03,c04,c05,c06,c07) }

  // ---- scanner: ring-8 read2; ONE counted wait per 4 timesteps (2 slots) ----
#define RD2A(PR, AD) asm volatile("ds_read2_b32 %0, %1 offset0:0 offset1:132" : "=v"(PR) : "v"(AD));
#define CONSUME(PR) {                                                                  \
    f32x2 cm_; asm("v_pk_add_f32 %0, %1, %2" : "=v"(cm_) : "v"(PR), "v"(negT2));       \
    float mP_ = fmaf(BETA, mem, PR[0]);                                                \
    float mM_ = fmaf(BETA, mem, cm_[0]);                                               \
    mem = sp ? mM_ : mP_;                                                              \
    sp  = mem > THR;                                                                   \
    cnt += sp ? 1u : 0u;                                                               \
    mP_ = fmaf(BETA, mem, PR[1]);                                                      \
    mM_ = fmaf(BETA, mem, cm_[1]);                                                     \
    mem = sp ? mM_ : mP_;                                                              \
    sp  = mem > THR;                                                                   \
    cnt += sp ? 1u : 0u; }

  // slot s covers t = 2s, 2s+1 at byte addr spB + s*1056
#define SFI(RGA, RGB, SA, SB) { LGW(6) CONSUME(pr##RGA) CONSUME(pr##RGB)               \
    { const uint32_t adA_ = spB + (uint32_t)((SA) * 1056); RD2A(pr##RGA, adA_) }       \
    { const uint32_t adB_ = spB + (uint32_t)((SB) * 1056); RD2A(pr##RGB, adB_) } }
#define SFT(RGA, RGB, W) { LGW(W) CONSUME(pr##RGA) CONSUME(pr##RGB) }

#define SCAN_PRE()                                                                     \
    f32x2 pr0, pr1, pr2, pr3, pr4, pr5, pr6, pr7;                                      \
    RD2A(pr0, spB)          RD2A(pr1, spB + 1056u)  RD2A(pr2, spB + 2112u)             \
    RD2A(pr3, spB + 3168u)  RD2A(pr4, spB + 4224u)  RD2A(pr5, spB + 5280u)             \
    RD2A(pr6, spB + 6336u)  RD2A(pr7, spB + 7392u)

#define SCAN_FULL() {                                                                  \
    SCAN_PRE()                                                                         \
    SFI(0,1,  8, 9) SFI(2,3, 10,11) SFI(4,5, 12,13) SFI(6,7, 14,15)                    \
    SFI(0,1, 16,17) SFI(2,3, 18,19) SFI(4,5, 20,21) SFI(6,7, 22,23)                    \
    SFI(0,1, 24,25) SFI(2,3, 26,27) SFI(4,5, 28,29) SFI(6,7, 30,31)                    \
    SFT(0,1,6) SFT(2,3,4) SFT(4,5,2) SFT(6,7,0) }

#define SCAN_TAIL() {                                                                  \
    SCAN_PRE()                                                                         \
    SFT(0,1,6) SFT(2,3,4) SFT(4,5,2) SFT(6,7,0) }

  const uint32_t spB0 = curB + (uint32_t)((swid * 64 + l) * 4);

  // ================= main phase loop =================
  if (isP) STAGE(0, 0);

#pragma unroll 1
  for (int ph = 0; ph <= NCH; ++ph) {
    if (isP) {
      if (ph <= NCH - 1) {
        VM0()
        if (ph < NCH - 1) STAGE(ph + 1, (ph + 1) & 1);
        const uint32_t pbuf = (uint32_t)(ph & 1);
        if (ph < NCH - 1) {
          GEMM2()
        } else if (pwid == 0) {
          GEMM_TAIL()
        }
        LGW(0)                                     // cur writes retired
      }
    } else {
      if (ph >= 1) {
        const uint32_t spB = spB0 + (uint32_t)(((ph - 1) & 1) * 33792);
        if (ph - 1 < NCH - 1) { SCAN_FULL() }
        else                  { SCAN_TAIL() }
        if (ph == NCH) cnt_s[swid * 64 + l] = (float)cnt;
      }
    }
    BAR()
  }

  __syncthreads();

  // ---- fused epilogue: logits from spike counts ----
  if (tid < Cdim) {
    float dot = 0.0f;
#pragma unroll
    for (int k = 0; k < Hdim; ++k)
      dot = fmaf(cnt_s[k], W2[tid * Hdim + k], dot);
    const float Tf = (float)Tdim;
    const float scale = 1.0f / Tf + 0.1f / (Tf + 1e-6f);
    out[b * Cdim + tid] = fmaf(dot, scale, 1.1f * b2[tid]);
  }
}

extern "C" void kernel_launch(void* const* d_in, const int* in_sizes, int n_in,
                              void* d_out, int out_size, void* d_ws, size_t ws_size,
                              hipStream_t stream) {
  const float* x  = (const float*)d_in[0];
  const float* W1 = (const float*)d_in[1];
  const float* b1 = (const float*)d_in[2];
  const float* W2 = (const float*)d_in[3];
  const float* b2 = (const float*)d_in[4];
  float* out = (float*)d_out;

  snn_spec4_kernel<<<dim3(Bdim), dim3(256), 0, stream>>>(x, W1, b1, W2, b2, out);
}

// Round 22
// 58.531 us; speedup vs baseline: 2.1006x; 1.0031x over previous
//
#include <hip/hip_runtime.h>
#include <stdint.h>

#define Bdim 512
#define Tdim 2000
#define Ddim 20
#define Hdim 128
#define Cdim 10
#define TT   64
#define NCH  32              // 31 full chunks + 16-step tail
#define BETA 0.95f
#define THR  0.8f

typedef float f32x2 __attribute__((ext_vector_type(2)));
typedef float f32x4 __attribute__((ext_vector_type(4)));
typedef int   i32x4 __attribute__((ext_vector_type(4)));

// f32 pair -> packed bf16 hi + packed bf16 lo (RNE)
#define CVT_HILO(HI, LO, F0, F1) {                                                     \
    asm volatile("v_cvt_pk_bf16_f32 %0, %1, %2" : "=v"(HI) : "v"(F0), "v"(F1));        \
    const float h0f_ = __uint_as_float((HI) << 16);                                    \
    const float h1f_ = __uint_as_float((HI) & 0xFFFF0000u);                            \
    const float l0_ = (F0) - h0f_;  const float l1_ = (F1) - h1f_;                     \
    asm volatile("v_cvt_pk_bf16_f32 %0, %1, %2" : "=v"(LO) : "v"(l0_), "v"(l1_)); }

#define MFMA0(ACC, A8, B8) \
  asm volatile("v_mfma_f32_16x16x32_bf16 %0, %1, %2, 0"  : "=v"(ACC) : "v"(A8), "v"(B8));
#define MFMA(ACC, A8, B8)  \
  asm volatile("v_mfma_f32_16x16x32_bf16 %0, %1, %2, %0" : "+v"(ACC) : "v"(A8), "v"(B8));

__global__ __launch_bounds__(256, 1) void snn_spec10_kernel(
    const float* __restrict__ x,   // [B,T,D]
    const float* __restrict__ W1,  // [H,D]
    const float* __restrict__ b1,  // [H]
    const float* __restrict__ W2,  // [C,H]
    const float* __restrict__ b2,  // [C]
    float* __restrict__ out)       // [B,C]
{
  const int b   = blockIdx.x;
  const int tid = threadIdx.x;    // 0..255
  const int wid = tid >> 6;
  const int l   = tid & 63;
  const int r   = l & 15;
  const int g   = l >> 4;

  // Role flip by block parity: co-resident blocks (b, b+256) then put one
  // producer AND one scanner on every SIMD instead of stacking same roles.
  const bool flip = ((b >> 8) & 1) != 0;
  const bool isP  = flip ? (wid >= 2) : (wid < 2);
  const int  pwid = wid & 1;      // producer index 0/1
  const int  swid = wid & 1;      // scanner index 0/1

  __shared__ __align__(16) float xraw[2][TT * Ddim];    // 10240 B
  __shared__ __align__(16) float cur[2][TT * 132];      // 67584 B, t-major stride 132 dw
  __shared__ float cnt_s[Hdim];

  const float* xb = x + (size_t)b * (Tdim * Ddim);
  const float* const clampMax = x + (size_t)Bdim * Tdim * Ddim - 4;

  const uint32_t xrawB = (uint32_t)(uintptr_t)&xraw[0][0];
  const uint32_t curB  = (uint32_t)(uintptr_t)&cur[0][0];

  // ---------------- producer-only setup ----------------
  i32x4 bhi[8], blo[8];
  f32x4 zero4, ovr;
  bool  sel23 = false, g3f = false;
  if (isP) {
    const bool g2 = (g == 2);
    g3f   = (g == 3);
    sel23 = g2 | g3f;
    zero4[0]=0.f; zero4[1]=0.f; zero4[2]=0.f; zero4[3]=0.f;
    ovr = zero4; if (g2) ovr[0] = 1.0f;    // bias rider at k=20
#pragma unroll
    for (int ni = 0; ni < 8; ++ni) {
      const int hh = ni * 16 + r;
      float wv[8];
#pragma unroll
      for (int j = 0; j < 8; ++j) {
        const int k = 8 * g + j;
        wv[j] = (k < Ddim) ? W1[hh * Ddim + k] : ((k == Ddim) ? b1[hh] : 0.0f);
      }
#pragma unroll
      for (int d = 0; d < 4; ++d) {
        const uint32_t u0 = __float_as_uint(wv[2*d]), u1 = __float_as_uint(wv[2*d+1]);
        const uint32_t h0 = (u0 + 0x8000u) & 0xFFFF0000u;
        const uint32_t h1 = (u1 + 0x8000u) & 0xFFFF0000u;
        bhi[ni][d] = (int)(h1 | (h0 >> 16));
        const float l0 = wv[2*d]   - __uint_as_float(h0);
        const float l1 = wv[2*d+1] - __uint_as_float(h1);
        const uint32_t e0 = (__float_as_uint(l0) + 0x8000u) & 0xFFFF0000u;
        const uint32_t e1 = (__float_as_uint(l1) + 0x8000u) & 0xFFFF0000u;
        blo[ni][d] = (int)(e1 | (e0 >> 16));
      }
    }
  }

  // ---------------- scanner-only state ----------------
  float    mem = 0.0f;
  bool     sp  = false;
  uint32_t cnt = 0u;
  f32x2    negT2; negT2[0] = -THR; negT2[1] = -THR;

#define STAGE(CH, BUF) do {                                                            \
    const float* g0_ = xb + (CH) * 1280 + pwid * 640 + l * 4;                          \
    char* lb_ = (char*)&xraw[0][0] + (BUF) * 5120 + pwid * 2560 + l * 16;              \
    const float* p0_ = g0_;        if (p0_ > clampMax) p0_ = clampMax;                 \
    const float* p1_ = g0_ + 256;  if (p1_ > clampMax) p1_ = clampMax;                 \
    __builtin_amdgcn_global_load_lds(                                                  \
      (const __attribute__((address_space(1))) unsigned int*)p0_,                      \
      (__attribute__((address_space(3))) unsigned int*)lb_, 16, 0, 0);                 \
    __builtin_amdgcn_global_load_lds(                                                  \
      (const __attribute__((address_space(1))) unsigned int*)p1_,                      \
      (__attribute__((address_space(3))) unsigned int*)(lb_ + 1024), 16, 0, 0);        \
    if (l < 32) {                                                                      \
      const float* p2_ = g0_ + 512;  if (p2_ > clampMax) p2_ = clampMax;               \
      __builtin_amdgcn_global_load_lds(                                                \
        (const __attribute__((address_space(1))) unsigned int*)p2_,                    \
        (__attribute__((address_space(3))) unsigned int*)(lb_ + 2048), 16, 0, 0);      \
    } } while (0)

#define VM0()  asm volatile("s_waitcnt vmcnt(0)" ::: "memory");
#define LGW(N) asm volatile("s_waitcnt lgkmcnt(" #N ")" ::: "memory"); __builtin_amdgcn_sched_barrier(0);
#define BAR()  __builtin_amdgcn_sched_barrier(0); __builtin_amdgcn_s_barrier(); __builtin_amdgcn_sched_barrier(0);

#define CW2(NI, AC)                                                                    \
    asm volatile("ds_write2_b32 %0, %1, %2 offset0:%c3 offset1:%c4"                    \
                 :: "v"(cwb_),  "v"(AC[0]), "v"(AC[1]), "n"(16*(NI)), "n"(16*(NI)+132)); \
    asm volatile("ds_write2_b32 %0, %1, %2 offset0:%c3 offset1:%c4"                    \
                 :: "v"(cwb2_), "v"(AC[2]), "v"(AC[3]), "n"(16*(NI)), "n"(16*(NI)+132));

#define CWRM(MTIDX, P0,P1,P2,P3,P4,P5,P6,P7) {                                         \
    const uint32_t cwb_  = curB + (uint32_t)(pbuf * 33792 + 528 * ((MTIDX) * 16 + 4 * g) + 4 * r); \
    const uint32_t cwb2_ = cwb_ + 1056u;                                               \
    CW2(0,P0) CW2(1,P1) CW2(2,P2) CW2(3,P3) CW2(4,P4) CW2(5,P5) CW2(6,P6) CW2(7,P7) }

#define SELA(A0, A1) { A0 = g3f ? zero4 : A0;  A1 = sel23 ? ovr : A1; }

#define CVT8(AHI, ALO, A0, A1) {                                                       \
    uint32_t h_, lo_;                                                                  \
    CVT_HILO(h_, lo_, A0[0], A0[1]) AHI[0]=(int)h_; ALO[0]=(int)lo_;                   \
    CVT_HILO(h_, lo_, A0[2], A0[3]) AHI[1]=(int)h_; ALO[1]=(int)lo_;                   \
    CVT_HILO(h_, lo_, A1[0], A1[1]) AHI[2]=(int)h_; ALO[2]=(int)lo_;                   \
    CVT_HILO(h_, lo_, A1[2], A1[3]) AHI[3]=(int)h_; ALO[3]=(int)lo_; }

#define MM24(AHI, ALO, C0,C1,C2,C3,C4,C5,C6,C7)                                        \
    MFMA0(C0, ALO, bhi[0]) MFMA0(C1, ALO, bhi[1]) MFMA0(C2, ALO, bhi[2])               \
    MFMA0(C3, ALO, bhi[3]) MFMA0(C4, ALO, bhi[4]) MFMA0(C5, ALO, bhi[5])               \
    MFMA0(C6, ALO, bhi[6]) MFMA0(C7, ALO, bhi[7])                                      \
    MFMA (C0, AHI, blo[0]) MFMA (C1, AHI, blo[1]) MFMA (C2, AHI, blo[2])               \
    MFMA (C3, AHI, blo[3]) MFMA (C4, AHI, blo[4]) MFMA (C5, AHI, blo[5])               \
    MFMA (C6, AHI, blo[6]) MFMA (C7, AHI, blo[7])                                      \
    MFMA (C0, AHI, bhi[0]) MFMA (C1, AHI, bhi[1]) MFMA (C2, AHI, bhi[2])               \
    MFMA (C3, AHI, bhi[3]) MFMA (C4, AHI, bhi[4]) MFMA (C5, AHI, bhi[5])               \
    MFMA (C6, AHI, bhi[6]) MFMA (C7, AHI, bhi[7])

  // Both 16-t tiles fused: 4 A-reads upfront, counted waits, all C-writes at end.
#define GEMM2() {                                                                      \
    const uint32_t afb_ = xrawB + (uint32_t)(pbuf * 5120 + (2*pwid) * 1280 + 80 * r + 32 * g); \
    f32x4 a00_, a01_, a10_, a11_;                                                      \
    asm volatile("ds_read_b128 %0, %1 offset:0"    : "=v"(a00_) : "v"(afb_));          \
    asm volatile("ds_read_b128 %0, %1 offset:16"   : "=v"(a01_) : "v"(afb_));          \
    asm volatile("ds_read_b128 %0, %1 offset:1280" : "=v"(a10_) : "v"(afb_));          \
    asm volatile("ds_read_b128 %0, %1 offset:1296" : "=v"(a11_) : "v"(afb_));          \
    LGW(2)                                                                             \
    SELA(a00_, a01_)                                                                   \
    i32x4 ahi0_, alo0_;  CVT8(ahi0_, alo0_, a00_, a01_)                                \
    asm volatile("s_nop 2");                                                           \
    f32x4 c00,c01,c02,c03,c04,c05,c06,c07;                                             \
    MM24(ahi0_, alo0_, c00,c01,c02,c03,c04,c05,c06,c07)                                \
    LGW(0)                                                                             \
    SELA(a10_, a11_)                                                                   \
    i32x4 ahi1_, alo1_;  CVT8(ahi1_, alo1_, a10_, a11_)                                \
    asm volatile("s_nop 2");                                                           \
    f32x4 c10,c11,c12,c13,c14,c15,c16,c17;                                             \
    MM24(ahi1_, alo1_, c10,c11,c12,c13,c14,c15,c16,c17)                                \
    asm volatile("s_nop 7"); asm volatile("s_nop 4");                                  \
    CWRM(2*pwid,     c00,c01,c02,c03,c04,c05,c06,c07)                                  \
    CWRM(2*pwid + 1, c10,c11,c12,c13,c14,c15,c16,c17) }

#define GEMM_TAIL() {                                                                  \
    const uint32_t afb_ = xrawB + (uint32_t)(pbuf * 5120 + 80 * r + 32 * g);           \
    f32x4 a00_, a01_;                                                                  \
    asm volatile("ds_read_b128 %0, %1 offset:0"  : "=v"(a00_) : "v"(afb_));            \
    asm volatile("ds_read_b128 %0, %1 offset:16" : "=v"(a01_) : "v"(afb_));            \
    LGW(0)                                                                             \
    SELA(a00_, a01_)                                                                   \
    i32x4 ahi0_, alo0_;  CVT8(ahi0_, alo0_, a00_, a01_)                                \
    asm volatile("s_nop 2");                                                           \
    f32x4 c00,c01,c02,c03,c04,c05,c06,c07;                                             \
    MM24(ahi0_, alo0_, c00,c01,c02,c03,c04,c05,c06,c07)                                \
    asm volatile("s_nop 7"); asm volatile("s_nop 4");                                  \
    CWRM(0, c00,c01,c02,c03,c04,c05,c06,c07) }

  // ---- scanner: ring-12 read2 (deeper prefetch cover vs r15's ring-8);
  //      consume order identical (slots 0..31 sequential) -> bit-identical math.
  //      12 outstanding < 15 lgkm cap; LGW(10) steady, 10->0 tail.
#define RD2A(PR, AD) asm volatile("ds_read2_b32 %0, %1 offset0:0 offset1:132" : "=v"(PR) : "v"(AD));
#define CONSUME(PR) {                                                                  \
    f32x2 cm_; asm("v_pk_add_f32 %0, %1, %2" : "=v"(cm_) : "v"(PR), "v"(negT2));       \
    float mP_ = fmaf(BETA, mem, PR[0]);                                                \
    float mM_ = fmaf(BETA, mem, cm_[0]);                                               \
    mem = sp ? mM_ : mP_;                                                              \
    sp  = mem > THR;                                                                   \
    cnt += sp ? 1u : 0u;                                                               \
    mP_ = fmaf(BETA, mem, PR[1]);                                                      \
    mM_ = fmaf(BETA, mem, cm_[1]);                                                     \
    mem = sp ? mM_ : mP_;                                                              \
    sp  = mem > THR;                                                                   \
    cnt += sp ? 1u : 0u; }

  // slot s covers t = 2s, 2s+1 at byte addr spB + s*1056
#define SFI(RGA, RGB, SA, SB) { LGW(10) CONSUME(pr##RGA) CONSUME(pr##RGB)              \
    { const uint32_t adA_ = spB + (uint32_t)((SA) * 1056); RD2A(pr##RGA, adA_) }       \
    { const uint32_t adB_ = spB + (uint32_t)((SB) * 1056); RD2A(pr##RGB, adB_) } }
#define SFT(RGA, RGB, W) { LGW(W) CONSUME(pr##RGA) CONSUME(pr##RGB) }

#define SCAN_PRE12()                                                                   \
    f32x2 pr0, pr1, pr2, pr3, pr4, pr5, pr6, pr7, pr8, pr9, pr10, pr11;                \
    RD2A(pr0,  spB)           RD2A(pr1,  spB + 1056u)   RD2A(pr2,  spB + 2112u)        \
    RD2A(pr3,  spB + 3168u)   RD2A(pr4,  spB + 4224u)   RD2A(pr5,  spB + 5280u)        \
    RD2A(pr6,  spB + 6336u)   RD2A(pr7,  spB + 7392u)   RD2A(pr8,  spB + 8448u)        \
    RD2A(pr9,  spB + 9504u)   RD2A(pr10, spB + 10560u)  RD2A(pr11, spB + 11616u)

#define SCAN_FULL() {                                                                  \
    SCAN_PRE12()                                                                       \
    SFI(0,1,  12,13) SFI(2,3,  14,15) SFI(4,5,  16,17)                                 \
    SFI(6,7,  18,19) SFI(8,9,  20,21) SFI(10,11,22,23)                                 \
    SFI(0,1,  24,25) SFI(2,3,  26,27) SFI(4,5,  28,29)                                 \
    SFI(6,7,  30,31)                                                                   \
    SFT(8,9,10) SFT(10,11,8) SFT(0,1,6) SFT(2,3,4) SFT(4,5,2) SFT(6,7,0) }

#define SCAN_TAIL() {                                                                  \
    f32x2 pr0, pr1, pr2, pr3, pr4, pr5, pr6, pr7;                                      \
    RD2A(pr0, spB)          RD2A(pr1, spB + 1056u)  RD2A(pr2, spB + 2112u)             \
    RD2A(pr3, spB + 3168u)  RD2A(pr4, spB + 4224u)  RD2A(pr5, spB + 5280u)             \
    RD2A(pr6, spB + 6336u)  RD2A(pr7, spB + 7392u)                                     \
    SFT(0,1,6) SFT(2,3,4) SFT(4,5,2) SFT(6,7,0) }

  const uint32_t spB0 = curB + (uint32_t)((swid * 64 + l) * 4);

  // ================= main phase loop =================
  if (isP) STAGE(0, 0);

#pragma unroll 1
  for (int ph = 0; ph <= NCH; ++ph) {
    if (isP) {
      if (ph <= NCH - 1) {
        VM0()
        if (ph < NCH - 1) STAGE(ph + 1, (ph + 1) & 1);
        const uint32_t pbuf = (uint32_t)(ph & 1);
        if (ph < NCH - 1) {
          GEMM2()
        } else if (pwid == 0) {
          GEMM_TAIL()
        }
        LGW(0)                                     // cur writes retired
      }
    } else {
      if (ph >= 1) {
        const uint32_t spB = spB0 + (uint32_t)(((ph - 1) & 1) * 33792);
        if (ph - 1 < NCH - 1) { SCAN_FULL() }
        else                  { SCAN_TAIL() }
        if (ph == NCH) cnt_s[swid * 64 + l] = (float)cnt;
      }
    }
    BAR()
  }

  __syncthreads();

  // ---- fused epilogue: logits from spike counts ----
  if (tid < Cdim) {
    float dot = 0.0f;
#pragma unroll
    for (int k = 0; k < Hdim; ++k)
      dot = fmaf(cnt_s[k], W2[tid * Hdim + k], dot);
    const float Tf = (float)Tdim;
    const float scale = 1.0f / Tf + 0.1f / (Tf + 1e-6f);
    out[b * Cdim + tid] = fmaf(dot, scale, 1.1f * b2[tid]);
  }
}

extern "C" void kernel_launch(void* const* d_in, const int* in_sizes, int n_in,
                              void* d_out, int out_size, void* d_ws, size_t ws_size,
                              hipStream_t stream) {
  const float* x  = (const float*)d_in[0];
  const float* W1 = (const float*)d_in[1];
  const float* b1 = (const float*)d_in[2];
  const float* W2 = (const float*)d_in[3];
  const float* b2 = (const float*)d_in[4];
  float* out = (float*)d_out;

  snn_spec10_kernel<<<dim3(Bdim), dim3(256), 0, stream>>>(x, W1, b1, W2, b2, out);
}